// Round 5
// baseline (1371.845 us; speedup 1.0000x reference)
//
#include <hip/hip_runtime.h>

// RegionFeatureLearner: 16 region LSTMs (H=100) over T=2..6 steps, batch 32768,
// + 1-step backward LSTM.
//
// R5: occupancy attack. R4 (2 waves/SIMD, 159KB LDS) was latency-exposed:
// MfmaUtil 18.6% == exactly the MFMA work floor, all pipes <55%. This round:
// 16-wave block (1024 thr), wave owns 16 rows, 4 waves/SIMD. Fits by
// compressing W' (k=106..127 are zeros): main [400][96] + tail [400][16]
// ([xw0..4,bias,0,0,hw96..99,0,0,0,0]) = 89.6KB, per-wave scratch 3.5KB,
// x per-step prefetched into named regs (no LDS x buffer, no dyn-index
// array) -> LDS 146.9KB, 1 block/CU = 4 waves/SIMD. All LDS rows
// XOR-swizzled (byte ^= (row&7)<<4) for uniform bank spread; h-store
// k-order remapped (col = tn + 24*quad) so quads write distinct words.
// Recurrence stays wave-local: ZERO barriers in the T loop (one barrier
// total, after W' staging). bwd: 512 thr, 4x32 rows, halves serial chain.

typedef _Float16 f16;
typedef _Float16 half2v __attribute__((ext_vector_type(2)));
typedef _Float16 half4v __attribute__((ext_vector_type(4)));
typedef _Float16 half8 __attribute__((ext_vector_type(8)));
typedef float floatx4 __attribute__((ext_vector_type(4)));

#define FEAT_STRIDE 310   // 62*5 floats per batch item

// LDS layout (bytes):
//   Wmain  @0      : [400 rows][96 halves] swizzled   = 76800
//   Wtail  @76800  : [400 rows][16 halves] swizzled   = 12800
//   scratch@89600  : per wave 3584 = [16][96h] main + [16][16h] tail, swz
#define LDS_WTAIL 76800
#define LDS_SCR   89600
#define SCR_WAVE  3584

__constant__ int c_pos[16][6] = {
 {3,0,1,2,4,0},{7,8,9,10,11,0},{5,6,0,0,0,0},{13,12,0,0,0,0},
 {14,15,23,24,32,33},{22,21,31,30,40,39},{16,17,18,19,20,0},{25,26,27,28,29,0},
 {34,35,36,37,38,0},{41,42,0,0,0,0},{49,48,0,0,0,0},{43,44,45,46,47,0},
 {50,51,57,0,0,0},{56,55,61,0,0,0},{52,53,54,0,0,0},{58,59,60,0,0,0}};
__constant__ int c_len[16] = {5,5,2,2,6,6,5,5,5,2,2,5,3,3,3,3};

__device__ __forceinline__ float sigf(float x) {
  return __builtin_amdgcn_rcpf(1.f + __builtin_amdgcn_exp2f(-1.44269504088896f * x));
}
__device__ __forceinline__ float tanhf_fast(float x) {
  // tanh(x) = 1 - 2/(exp(2x)+1)
  return 1.f - 2.f * __builtin_amdgcn_rcpf(1.f + __builtin_amdgcn_exp2f(2.88539008177793f * x));
}
__device__ __forceinline__ half8 hzero8() {
  half8 z = {(f16)0,(f16)0,(f16)0,(f16)0,(f16)0,(f16)0,(f16)0,(f16)0};
  return z;
}

// ---------------------------------------------------------------------------
// Prep: W'[r][N'=4j+g][112] fp16. Main cols c=0..95 hold Whh in the PERMUTED
// k-order k(c) = 4*(c%24) + c/24 (matches h-store col = tn + 24*quad).
// Tail cols 96..111 = [xw0..xw4, bias, 0, 0, hw96..99, 0, 0, 0, 0].
// Original gate row = g*100 + j (i,f,g,o chunks), forward direction.
// ---------------------------------------------------------------------------
__global__ __launch_bounds__(256) void prep_kernel(
    const float* __restrict__ w_ih, const float* __restrict__ w_hh,
    const float* __restrict__ b_ih, const float* __restrict__ b_hh,
    f16* __restrict__ wp)
{
  int id = blockIdx.x * 256 + threadIdx.x;
  if (id >= 16 * 400 * 112) return;
  int c = id % 112;
  int rowN = (id / 112) % 400;
  int r = id / (112 * 400);
  int j = rowN >> 2, g = rowN & 3;
  int orig = (r * 2 + 0) * 400 + g * 100 + j;   // forward direction (dir=0)
  float v;
  if (c < 96) {
    int k = 4 * (c % 24) + (c / 24);            // permuted k-order
    v = w_hh[orig * 100 + k];
  } else {
    int tc = c - 96;
    if (tc < 5)               v = w_ih[orig * 5 + tc];
    else if (tc == 5)         v = b_ih[orig] + b_hh[orig];
    else if (tc >= 8 && tc < 12) v = w_hh[orig * 100 + 96 + (tc - 8)];
    else                      v = 0.f;
  }
  wp[id] = (f16)v;
}

// ---------------------------------------------------------------------------
// Forward: block = (region r, 256 batch rows) = 16 waves x 16 rows.
// Each wave computes all 400 gate rows (25 N'-tiles) for its 16 rows; the
// recurrence is wave-local (barrier-free). Per step: 3 main MFMAs (k=0..95,
// permuted order) + 1 tail MFMA (x/bias/h96..99; quads 2,3 carry zeros).
// ---------------------------------------------------------------------------
__global__ __launch_bounds__(1024, 4) void fwd_kernel(
    const float* __restrict__ feat, const f16* __restrict__ wp,
    float* __restrict__ out)
{
  __shared__ __align__(16) unsigned char lds[146944];

  const int bx = blockIdx.x;
  const int r  = bx >> 7;               // 128 m-blocks per region
  const int n0 = (bx & 127) << 8;       // 256 batch rows per block
  const int tid  = threadIdx.x;
  const int wave = tid >> 6;
  const int lane = tid & 63;
  const int quad = lane >> 4;
  const int l15  = lane & 15;
  const int T = c_len[r];
  const int m_self = n0 + wave * 16 + l15;

  // ---- zero this wave's scratch (wave-private; ordered by barrier below)
  {
    unsigned char* scr = lds + LDS_SCR + wave * SCR_WAVE;
    for (int i = lane; i < SCR_WAVE / 16; i += 64) {
      floatx4 z = {0.f, 0.f, 0.f, 0.f};
      *(floatx4*)(scr + 16 * i) = z;
    }
  }
  // ---- stage W' -> LDS, swizzled (byte ^= (row&7)<<4 within each row)
  {
    const f16* wr = wp + (size_t)r * 400 * 112;
    for (int idx = tid; idx < 400 * 14; idx += 1024) {
      int row = idx / 14, c = idx - row * 14;
      half8 v = *(const half8*)(wr + row * 112 + 8 * c);
      int sw = (row & 7) << 4;
      int dst = (c < 12) ? ((row * 192 + c * 16) ^ sw)
                         : (LDS_WTAIL + ((row * 32 + (c - 12) * 16) ^ sw));
      *(half8*)(lds + dst) = v;
    }
  }
  // ---- load x_0 (quad==1 lanes are the x writers)
  float nx0, nx1, nx2, nx3, nx4;
  if (quad == 1) {
    const float* fb = feat + (size_t)m_self * FEAT_STRIDE + c_pos[r][0] * 5;
    nx0 = fb[0]; nx1 = fb[1]; nx2 = fb[2]; nx3 = fb[3]; nx4 = fb[4];
  }
  __syncthreads();   // the ONLY block-wide barrier

  unsigned char* Sm = lds + LDS_SCR + wave * SCR_WAVE;   // [16][96h] swz
  unsigned char* St = Sm + 3072;                         // [16][16h] swz
  const int swz = (l15 & 7) << 4;

  // write x_0 into tail cols 0..5 ([x0..x4, 1.0]); cols 6,7,12..15 stay 0
  if (quad == 1) {
    half4v xa; xa[0] = (f16)nx0; xa[1] = (f16)nx1; xa[2] = (f16)nx2; xa[3] = (f16)nx3;
    half2v xb; xb[0] = (f16)nx4; xb[1] = (f16)1.0f;
    *(half4v*)(St + ((l15 * 32) ^ swz)) = xa;
    *(half2v*)(St + ((l15 * 32 + 8) ^ swz)) = xb;
  }

  float creg[25];
  #pragma unroll
  for (int tn = 0; tn < 25; ++tn) creg[tn] = 0.f;

  for (int t = 0; t < T; ++t) {
    const bool notlast = (t + 1 < T);

    // ---- B fragments (this wave's scratch; reads precede all writes)
    half8 bf0 = *(const half8*)(Sm + ((l15 * 192 +   0 + quad * 16) ^ swz));
    half8 bf1 = *(const half8*)(Sm + ((l15 * 192 +  64 + quad * 16) ^ swz));
    half8 bf2 = *(const half8*)(Sm + ((l15 * 192 + 128 + quad * 16) ^ swz));
    half8 bf3 = hzero8();
    if (quad < 2)
      bf3 = *(const half8*)(St + ((l15 * 32 + quad * 16) ^ swz));

    // ---- prefetch next step's x (consumed ~after the tile loop)
    if (notlast && quad == 1) {
      const float* fb = feat + (size_t)m_self * FEAT_STRIDE + c_pos[r][t + 1] * 5;
      nx0 = fb[0]; nx1 = fb[1]; nx2 = fb[2]; nx3 = fb[3]; nx4 = fb[4];
    }

    #pragma unroll
    for (int tn = 0; tn < 25; ++tn) {
      const int rb = (16 * tn + l15) * 192;
      const int tb = (16 * tn + l15) * 32;
      half8 wf0 = *(const half8*)(lds + ((rb +   0 + quad * 16) ^ swz));
      half8 wf1 = *(const half8*)(lds + ((rb +  64 + quad * 16) ^ swz));
      half8 wf2 = *(const half8*)(lds + ((rb + 128 + quad * 16) ^ swz));
      half8 wf3 = hzero8();
      if (quad < 2)
        wf3 = *(const half8*)(lds + LDS_WTAIL + ((tb + quad * 16) ^ swz));

      floatx4 acc = {0.f, 0.f, 0.f, 0.f};
      acc = __builtin_amdgcn_mfma_f32_16x16x32_f16(wf0, bf0, acc, 0, 0, 0);
      acc = __builtin_amdgcn_mfma_f32_16x16x32_f16(wf1, bf1, acc, 0, 0, 0);
      acc = __builtin_amdgcn_mfma_f32_16x16x32_f16(wf2, bf2, acc, 0, 0, 0);
      acc = __builtin_amdgcn_mfma_f32_16x16x32_f16(wf3, bf3, acc, 0, 0, 0);

      // lane holds gates i,f,g,o of (m = m_self, j = 4*tn+quad)
      float ig = sigf(acc[0]);
      float fg = sigf(acc[1]);
      float gg = tanhf_fast(acc[2]);
      float og = sigf(acc[3]);
      float cn = fg * creg[tn] + ig * gg;
      creg[tn] = cn;
      float hv = og * tanhf_fast(cn);

      if (notlast) {
        if (tn < 24) {
          // permuted k-order: col = tn + 24*quad -> quads hit distinct words
          *(f16*)(Sm + ((l15 * 192 + (tn + 24 * quad) * 2) ^ swz)) = (f16)hv;
        } else {
          // j = 96+quad -> tail col 8+quad
          *(f16*)(St + ((l15 * 32 + 16 + 2 * quad) ^ swz)) = (f16)hv;
        }
      } else {
        out[(size_t)m_self * 3200 + r * 200 + 4 * tn + quad] = hv;
      }
    }

    // ---- write next x into tail (after this step's tail read; DS in-order)
    if (notlast && quad == 1) {
      half4v xa; xa[0] = (f16)nx0; xa[1] = (f16)nx1; xa[2] = (f16)nx2; xa[3] = (f16)nx3;
      half2v xb; xb[0] = (f16)nx4; xb[1] = (f16)1.0f;
      *(half4v*)(St + ((l15 * 32) ^ swz)) = xa;
      *(half2v*)(St + ((l15 * 32 + 8) ^ swz)) = xb;
    }
  }
}

// ---------------------------------------------------------------------------
// Backward: single step with h0=c0=0 => g = x_last @ Wih_b^T + bias; f unused.
// Block = (region, 128 batch rows), 512 threads. Threads 0..399: thread owns
// one (jj, 32-row quarter); weights in 18 registers.
// ---------------------------------------------------------------------------
__global__ __launch_bounds__(512) void bwd_kernel(
    const float* __restrict__ feat, const float* __restrict__ w_ih,
    const float* __restrict__ b_ih, const float* __restrict__ b_hh,
    float* __restrict__ out)
{
  __shared__ float wg[300 * 7];   // rows: i(0..99) g(100..199) o(200..299); [w0..w4,bias,pad]
  __shared__ float xs[128 * 5];
  const int bx = blockIdx.x;
  const int r  = bx >> 8;          // 256 n-chunks per region
  const int n0 = (bx & 255) << 7;  // 128 rows per block
  const int tid = threadIdx.x;
  const int pos = c_pos[r][c_len[r] - 1];

  for (int i = tid; i < 2100; i += 512) {
    int row = i / 7, c = i - row * 7;
    int q = row / 100, jj = row - q * 100;
    int qq = (q == 0) ? 0 : (q + 1);            // 0->i, 1->g(2), 2->o(3)
    int orig = (r * 2 + 1) * 400 + qq * 100 + jj;  // backward direction (dir=1)
    float v = 0.f;
    if (c < 5)       v = w_ih[orig * 5 + c];
    else if (c == 5) v = b_ih[orig] + b_hh[orig];
    wg[i] = v;
  }
  for (int i = tid; i < 640; i += 512) {
    int nl = i / 5, s = i - nl * 5;
    xs[i] = feat[(size_t)(n0 + nl) * FEAT_STRIDE + pos * 5 + s];
  }
  __syncthreads();

  if (tid < 400) {
    const int g  = tid / 100;        // which 32-row quarter
    const int jj = tid - g * 100;
    const float* wi = wg + jj * 7;
    const float* wc = wg + (100 + jj) * 7;
    const float* wo = wg + (200 + jj) * 7;
    float i0 = wi[0], i1 = wi[1], i2 = wi[2], i3 = wi[3], i4 = wi[4], ib = wi[5];
    float c0 = wc[0], c1 = wc[1], c2 = wc[2], c3 = wc[3], c4 = wc[4], cb = wc[5];
    float o0 = wo[0], o1 = wo[1], o2 = wo[2], o3 = wo[3], o4 = wo[4], ob = wo[5];
    for (int i = 0; i < 32; ++i) {
      int nl = g * 32 + i;
      const float* xp = xs + nl * 5;
      float x0 = xp[0], x1 = xp[1], x2 = xp[2], x3 = xp[3], x4 = xp[4];
      float gi = ib + i0*x0 + i1*x1 + i2*x2 + i3*x3 + i4*x4;
      float gc = cb + c0*x0 + c1*x1 + c2*x2 + c3*x3 + c4*x4;
      float go = ob + o0*x0 + o1*x1 + o2*x2 + o3*x3 + o4*x4;
      float cc = sigf(gi) * tanhf_fast(gc);
      float hh = sigf(go) * tanhf_fast(cc);
      out[(size_t)(n0 + nl) * 3200 + r * 200 + 100 + jj] = hh;
    }
  }
}

extern "C" void kernel_launch(void* const* d_in, const int* in_sizes, int n_in,
                              void* d_out, int out_size, void* d_ws, size_t ws_size,
                              hipStream_t stream) {
  const float* feat = (const float*)d_in[0];
  const float* w_ih = (const float*)d_in[1];
  const float* w_hh = (const float*)d_in[2];
  const float* b_ih = (const float*)d_in[3];
  const float* b_hh = (const float*)d_in[4];
  float* out = (float*)d_out;
  f16* wp = (f16*)d_ws;   // 16*400*112*2 = 1.43 MB

  prep_kernel<<<2800, 256, 0, stream>>>(w_ih, w_hh, b_ih, b_hh, wp);
  fwd_kernel<<<2048, 1024, 0, stream>>>(feat, wp, out);
  bwd_kernel<<<4096, 512, 0, stream>>>(feat, w_ih, b_ih, b_hh, out);
}